// Round 2
// baseline (133.756 us; speedup 1.0000x reference)
//
#include <hip/hip_runtime.h>

// Per-row token-count histogram:
//   x: (B=1024, S=2048) int32 tokens in [0, 32128)
//   out: (B, V=32128) float32 counts
// Memory-bound: 131.6 MB output write dominates. One block per row,
// u16-packed LDS histogram (62.75 KiB), single coalesced output pass.

#define VOCAB 32128
#define WORDS (VOCAB / 2)   // 16064 u32 words, each holds two u16 bins
#define SEQ 2048
#define BLOCK 512

__global__ __launch_bounds__(BLOCK, 4) void hist_rows_kernel(
    const int* __restrict__ x, float* __restrict__ out) {
    // Packed counts: word w holds bins 2w (low u16) and 2w+1 (high u16).
    // Max per-bin count = SEQ = 2048 < 65536 -> no carry into neighbor.
    __shared__ unsigned int cnt[WORDS];

    const int row = blockIdx.x;
    const int tid = threadIdx.x;

    // --- Phase 1: zero LDS (uint4 = 16B per write) ---
    uint4* c4 = reinterpret_cast<uint4*>(cnt);
    #pragma unroll
    for (int i = tid; i < WORDS / 4; i += BLOCK) {   // 4016 / 512 ≈ 8 iters
        c4[i] = make_uint4(0u, 0u, 0u, 0u);
    }
    __syncthreads();

    // --- Phase 2: scatter tokens (int4 vector loads, LDS atomics) ---
    const int4* xrow = reinterpret_cast<const int4*>(x + (size_t)row * SEQ);
    for (int i = tid; i < SEQ / 4; i += BLOCK) {     // 512 / 512 = 1 iter
        int4 t = xrow[i];
        atomicAdd(&cnt[t.x >> 1], 1u << ((t.x & 1) * 16));
        atomicAdd(&cnt[t.y >> 1], 1u << ((t.y & 1) * 16));
        atomicAdd(&cnt[t.z >> 1], 1u << ((t.z & 1) * 16));
        atomicAdd(&cnt[t.w >> 1], 1u << ((t.w & 1) * 16));
    }
    __syncthreads();

    // --- Phase 3: expand u16 -> f32, coalesced float4 stores ---
    // Each iteration reads 2 LDS words (4 bins) and writes one float4.
    float4* orow = reinterpret_cast<float4*>(out + (size_t)row * VOCAB);
    const uint2* c2 = reinterpret_cast<const uint2*>(cnt);
    for (int i = tid; i < WORDS / 2; i += BLOCK) {   // 8032 / 512 ≈ 16 iters
        uint2 w = c2[i];
        float4 f;
        f.x = (float)(w.x & 0xFFFFu);
        f.y = (float)(w.x >> 16);
        f.z = (float)(w.y & 0xFFFFu);
        f.w = (float)(w.y >> 16);
        orow[i] = f;
    }
}

extern "C" void kernel_launch(void* const* d_in, const int* in_sizes, int n_in,
                              void* d_out, int out_size, void* d_ws, size_t ws_size,
                              hipStream_t stream) {
    const int* x = (const int*)d_in[0];
    float* out = (float*)d_out;
    const int B = in_sizes[0] / SEQ;  // 1024
    hipLaunchKernelGGL(hist_rows_kernel, dim3(B), dim3(BLOCK), 0, stream, x, out);
}